// Round 10
// baseline (202.261 us; speedup 1.0000x reference)
//
#include <hip/hip_runtime.h>
#include <math.h>

#define N_NODES 50000
#define N_EDGES 800000
#define EPS 1e-7f
#define NEG_SLOPE 0.01f

#define BUCKET 64                    // max degree bound (mean=16, Poisson; safe)
#define EDGE_BLOCKS (N_EDGES / 256)  // 3125

typedef __attribute__((ext_vector_type(8))) short short8;
typedef __attribute__((ext_vector_type(4))) float f32x4;

// round-to-nearest-even bf16 (low 16 bits of result)
__device__ __forceinline__ unsigned bf16_rne(float x) {
    unsigned u = __float_as_uint(x);
    u += 0x7fffu + ((u >> 16) & 1u);
    return u >> 16;
}
__device__ __forceinline__ unsigned pack_bf16(float a, float b) {
    return bf16_rne(a) | (bf16_rne(b) << 16);
}

// ---------------- pass 1: histogram + 4B src scatter + weight pack ----------------

__global__ __launch_bounds__(256) void prep_kernel(
    const int* __restrict__ src, const int* __restrict__ dst,
    int* __restrict__ cnt, unsigned* __restrict__ sbuf,
    const float* __restrict__ W_neigh, const float* __restrict__ W_self,
    const float* __restrict__ b_neigh, const float* __restrict__ bias,
    unsigned* __restrict__ wnp, unsigned* __restrict__ wsp, float* __restrict__ bb)
{
    const int bid = blockIdx.x;

    if (bid == EDGE_BLOCKS) {  // weight-pack block
        const int t = threadIdx.x;
        const float2* Wn2 = (const float2*)W_neigh;
        const float2* Ws2 = (const float2*)W_self;
        for (int i = t; i < 64 * 128; i += 256) {
            float2 v = Wn2[i];
            wnp[i] = pack_bf16(v.x, v.y);
        }
        for (int i = t; i < 64 * 32; i += 256) {
            float2 v = Ws2[i];
            wsp[i] = pack_bf16(v.x, v.y);
        }
        if (t < 64) bb[t] = b_neigh[t] + bias[t];
        return;
    }

    const int i = bid * 256 + threadIdx.x;  // 3125*256 == 800000 exact
    const int s = src[i], d = dst[i];
    const int p = atomicAdd(&cnt[d], 1);
    if (p < BUCKET) sbuf[(size_t)d * BUCKET + p] = (unsigned)s;
}

// ---------------- pass 2: fused aggregation + MFMA projection ----------------
// Block = 4 waves = 16 nodes. Per node: lane e computes edge e's geometry in
// registers (vectorized pos gather + rsqrt), then the per-edge loop broadcasts
// (wx,wy,wz,src) via v_readlane — no record memory stream at all.

#define ACC_STRIDE 264  // bf16 elements per LDS row (256 + 8 pad; keeps 16B align)

__device__ __forceinline__ short8 feat_frag_bf16(const float* p) {
    float4 x0 = *reinterpret_cast<const float4*>(p);
    float4 x1 = *reinterpret_cast<const float4*>(p + 4);
    union { unsigned u[4]; short8 s; } c;
    c.u[0] = pack_bf16(x0.x, x0.y);
    c.u[1] = pack_bf16(x0.z, x0.w);
    c.u[2] = pack_bf16(x1.x, x1.y);
    c.u[3] = pack_bf16(x1.z, x1.w);
    return c.s;
}

__global__ __launch_bounds__(256) void aggregate_project_kernel(
    const float* __restrict__ feat, const float* __restrict__ pos,
    const float* __restrict__ W_sp, const float* __restrict__ b_sp,
    const int* __restrict__ cnt, const unsigned* __restrict__ sbuf,
    const short* __restrict__ wnb, const short* __restrict__ wsb,
    const float* __restrict__ bb, float* __restrict__ out)
{
    __shared__ unsigned short accS[16 * ACC_STRIDE];  // 8448 B

    const int lane = threadIdx.x & 63;
    const int w = threadIdx.x >> 6;
    const int nb = blockIdx.x << 4;  // 3125*16 == 50000 exact

    // per-lane spatial-MLP rows: lane = feature i, handles j = lane*4+h
    float wsp0[4], wsp1[4], wsp2[4], bsp[4];
#pragma unroll
    for (int h = 0; h < 4; ++h) {
        int j = lane * 4 + h;
        wsp0[h] = W_sp[j * 3 + 0];
        wsp1[h] = W_sp[j * 3 + 1];
        wsp2[h] = W_sp[j * 3 + 2];
        bsp[h]  = b_sp[j];
    }

    // ---- aggregation: wave w handles rows 4w..4w+3, one node at a time ----
    for (int q = 0; q < 4; ++q) {
        const int r = (w << 2) + q;
        const int n = nb + r;
        const int degt = __builtin_amdgcn_readfirstlane(cnt[n]);
        const int deg = min(degt, BUCKET);

        float a0 = 0.f, a1 = 0.f, a2 = 0.f, a3 = 0.f;

        if (deg > 0) {
            // vector phase: lane = edge. ws is 0xAA-poisoned -> clamp unused lanes.
            unsigned svr = sbuf[(size_t)n * BUCKET + lane];
            const unsigned sv = (lane < deg) ? svr : 0u;
            const float pdx = pos[n * 3 + 0];
            const float pdy = pos[n * 3 + 1];
            const float pdz = pos[n * 3 + 2];
            const float rx = pdx - pos[sv * 3 + 0];
            const float ry = pdy - pos[sv * 3 + 1];
            const float rz = pdz - pos[sv * 3 + 2];
            const float inv =
                __builtin_amdgcn_rcpf(__builtin_amdgcn_sqrtf(rx * rx + ry * ry + rz * rz) + EPS);
            // per-lane packed record: (bf16 wx | bf16 wy), (bf16 wz | src<<16)
            const unsigned rx0 = pack_bf16((rx + 1.f) * inv, (ry + 1.f) * inv);
            const unsigned rx1 = bf16_rne((rz + 1.f) * inv) | (sv << 16);

            const int dm = deg - 1;
            // broadcast phase with depth-2 feat prefetch
            uint2 u0 = make_uint2((unsigned)__builtin_amdgcn_readlane((int)rx0, 0),
                                  (unsigned)__builtin_amdgcn_readlane((int)rx1, 0));
            const int e1i = min(1, dm);
            uint2 u1 = make_uint2((unsigned)__builtin_amdgcn_readlane((int)rx0, e1i),
                                  (unsigned)__builtin_amdgcn_readlane((int)rx1, e1i));
            float f0 = feat[(size_t)(u0.y >> 16) * 64 + lane];
            float f1 = feat[(size_t)(u1.y >> 16) * 64 + lane];

            for (int e = 0; e < deg; e += 2) {
                const int e2i = min(e + 2, dm);
                const int e3i = min(e + 3, dm);
                uint2 u2 = make_uint2((unsigned)__builtin_amdgcn_readlane((int)rx0, e2i),
                                      (unsigned)__builtin_amdgcn_readlane((int)rx1, e2i));
                uint2 u3 = make_uint2((unsigned)__builtin_amdgcn_readlane((int)rx0, e3i),
                                      (unsigned)__builtin_amdgcn_readlane((int)rx1, e3i));
                float f2 = feat[(size_t)(u2.y >> 16) * 64 + lane];
                float f3 = feat[(size_t)(u3.y >> 16) * 64 + lane];

                {
                    const float wx = __uint_as_float(u0.x << 16);
                    const float wy = __uint_as_float(u0.x & 0xffff0000u);
                    const float wz = __uint_as_float(u0.y << 16);
                    float t0 = fmaf(wx, wsp0[0], fmaf(wy, wsp1[0], fmaf(wz, wsp2[0], bsp[0])));
                    float t1 = fmaf(wx, wsp0[1], fmaf(wy, wsp1[1], fmaf(wz, wsp2[1], bsp[1])));
                    float t2 = fmaf(wx, wsp0[2], fmaf(wy, wsp1[2], fmaf(wz, wsp2[2], bsp[2])));
                    float t3 = fmaf(wx, wsp0[3], fmaf(wy, wsp1[3], fmaf(wz, wsp2[3], bsp[3])));
                    a0 = fmaf(fmaxf(t0, t0 * NEG_SLOPE), f0, a0);
                    a1 = fmaf(fmaxf(t1, t1 * NEG_SLOPE), f0, a1);
                    a2 = fmaf(fmaxf(t2, t2 * NEG_SLOPE), f0, a2);
                    a3 = fmaf(fmaxf(t3, t3 * NEG_SLOPE), f0, a3);
                }
                {
                    const float m1 = (e + 1 <= dm) ? 1.f : 0.f;
                    const float fm = f1 * m1;
                    const float wx = __uint_as_float(u1.x << 16);
                    const float wy = __uint_as_float(u1.x & 0xffff0000u);
                    const float wz = __uint_as_float(u1.y << 16);
                    float t0 = fmaf(wx, wsp0[0], fmaf(wy, wsp1[0], fmaf(wz, wsp2[0], bsp[0])));
                    float t1 = fmaf(wx, wsp0[1], fmaf(wy, wsp1[1], fmaf(wz, wsp2[1], bsp[1])));
                    float t2 = fmaf(wx, wsp0[2], fmaf(wy, wsp1[2], fmaf(wz, wsp2[2], bsp[2])));
                    float t3 = fmaf(wx, wsp0[3], fmaf(wy, wsp1[3], fmaf(wz, wsp2[3], bsp[3])));
                    a0 = fmaf(fmaxf(t0, t0 * NEG_SLOPE), fm, a0);
                    a1 = fmaf(fmaxf(t1, t1 * NEG_SLOPE), fm, a1);
                    a2 = fmaf(fmaxf(t2, t2 * NEG_SLOPE), fm, a2);
                    a3 = fmaf(fmaxf(t3, t3 * NEG_SLOPE), fm, a3);
                }

                u0 = u2; u1 = u3; f0 = f2; f1 = f3;
            }
        }

        const float mscale = 1.f / fmaxf((float)degt, 1.f);
        uint2 pv = make_uint2(pack_bf16(a0 * mscale, a1 * mscale),
                              pack_bf16(a2 * mscale, a3 * mscale));
        *reinterpret_cast<uint2*>(&accS[r * ACC_STRIDE + lane * 4]) = pv;
    }
    __syncthreads();

    // ---- projection: wave w -> output col-tile w (cols w*16..w*16+15) ----
    const int mrow = lane & 15;
    const int quad = lane >> 4;
    const int o = (w << 4) + mrow;

    f32x4 acc = {0.f, 0.f, 0.f, 0.f};

    const unsigned short* Ar = &accS[mrow * ACC_STRIDE + quad * 8];
    const short* Br = wnb + o * 256 + quad * 8;
#pragma unroll
    for (int ks = 0; ks < 8; ++ks) {
        short8 a = *reinterpret_cast<const short8*>(Ar + ks * 32);
        short8 b = *reinterpret_cast<const short8*>(Br + ks * 32);
        acc = __builtin_amdgcn_mfma_f32_16x16x32_bf16(a, b, acc, 0, 0, 0);
    }

    const float* Fr = feat + (size_t)(nb + mrow) * 64 + quad * 8;
    const short* Sr = wsb + o * 64 + quad * 8;
#pragma unroll
    for (int ks = 0; ks < 2; ++ks) {
        short8 a = feat_frag_bf16(Fr + ks * 32);
        short8 b = *reinterpret_cast<const short8*>(Sr + ks * 32);
        acc = __builtin_amdgcn_mfma_f32_16x16x32_bf16(a, b, acc, 0, 0, 0);
    }

    const float badd = bb[o];
#pragma unroll
    for (int r = 0; r < 4; ++r) {
        out[(size_t)(nb + quad * 4 + r) * 64 + o] = acc[r] + badd;
    }
}

// ---------------- launch ----------------

extern "C" void kernel_launch(void* const* d_in, const int* in_sizes, int n_in,
                              void* d_out, int out_size, void* d_ws, size_t ws_size,
                              hipStream_t stream) {
    (void)in_sizes; (void)n_in; (void)out_size; (void)ws_size;
    const float* feat    = (const float*)d_in[0];
    const float* pos     = (const float*)d_in[1];
    const int*   src     = (const int*)d_in[2];
    const int*   dst     = (const int*)d_in[3];
    const float* W_self  = (const float*)d_in[4];
    const float* W_sp    = (const float*)d_in[5];
    const float* b_sp    = (const float*)d_in[6];
    const float* W_neigh = (const float*)d_in[7];
    const float* b_neigh = (const float*)d_in[8];
    const float* bias    = (const float*)d_in[9];
    float* out = (float*)d_out;

    // ws layout: sbuf[N*64] uint (12.8 MB) | wnp[8192] | wsp[2048] | bb[64]f | cnt[N]
    unsigned int* sbuf = (unsigned int*)d_ws;
    unsigned int* wnp  = sbuf + (size_t)N_NODES * BUCKET;
    unsigned int* wsp  = wnp + 8192;
    float*        bb   = (float*)(wsp + 2048);
    int*          cnt  = (int*)(bb + 64);

    hipMemsetAsync(cnt, 0, (size_t)N_NODES * sizeof(int), stream);
    prep_kernel<<<EDGE_BLOCKS + 1, 256, 0, stream>>>(
        src, dst, cnt, sbuf, W_neigh, W_self, b_neigh, bias, wnp, wsp, bb);
    aggregate_project_kernel<<<N_NODES / 16, 256, 0, stream>>>(
        feat, pos, W_sp, b_sp, cnt, sbuf, (const short*)wnp, (const short*)wsp, bb, out);
}

// Round 12
// 189.971 us; speedup vs baseline: 1.0647x; 1.0647x over previous
//
#include <hip/hip_runtime.h>
#include <math.h>

#define N_NODES 50000
#define N_EDGES 800000
#define EPS 1e-7f
#define NEG_SLOPE 0.01f

#define BUCKET 64                    // max records kept per node (Poisson mean 16)
#define EDGE_BLOCKS (N_EDGES / 256)  // 3125
#define FEAT_BLOCKS (N_NODES * 64 / 4 / 256)  // 3125 (4 floats per thread)

typedef __attribute__((ext_vector_type(8))) short short8;
typedef __attribute__((ext_vector_type(4))) float f32x4;

// round-to-nearest-even bf16 (low 16 bits of result)
__device__ __forceinline__ unsigned bf16_rne(float x) {
    unsigned u = __float_as_uint(x);
    u += 0x7fffu + ((u >> 16) & 1u);
    return u >> 16;
}
__device__ __forceinline__ unsigned pack_bf16(float a, float b) {
    return bf16_rne(a) | (bf16_rne(b) << 16);
}

// ---------------- pass 1: direct-bucket CSR + geometry + feat/weight pack ----------------
// gdata[d*gstride+p]: u.x = bf16(wx)|bf16(wy)<<16 ; u.y = bf16(wz)|src<<16 (src < 65536)
// gstride = 72 (576B): de-aliases the scalar cache (512B stride maps to 8 sets; 576B to all 64)

__global__ __launch_bounds__(256) void prep_kernel(
    const int* __restrict__ src, const int* __restrict__ dst,
    const float* __restrict__ pos, const float* __restrict__ feat,
    int* __restrict__ cnt, uint2* __restrict__ gdata, int gstride,
    uint2* __restrict__ featb2,
    const float* __restrict__ W_neigh, const float* __restrict__ W_self,
    const float* __restrict__ b_neigh, const float* __restrict__ bias,
    unsigned* __restrict__ wnp, unsigned* __restrict__ wsp, float* __restrict__ bb)
{
    const int bid = blockIdx.x;

    if (bid < EDGE_BLOCKS) {  // per-edge geometry -> direct bucket write
        const int i = bid * 256 + threadIdx.x;  // 3125*256 == 800000 exact
        const int s = src[i], d = dst[i];
        const float sx = pos[s * 3 + 0], sy = pos[s * 3 + 1], sz = pos[s * 3 + 2];
        const float dx = pos[d * 3 + 0], dy = pos[d * 3 + 1], dz = pos[d * 3 + 2];
        const float rx = dx - sx, ry = dy - sy, rz = dz - sz;
        const float inv =
            __builtin_amdgcn_rcpf(__builtin_amdgcn_sqrtf(rx * rx + ry * ry + rz * rz) + EPS);
        const uint2 rec = make_uint2(pack_bf16((rx + 1.f) * inv, (ry + 1.f) * inv),
                                     bf16_rne((rz + 1.f) * inv) | ((unsigned)s << 16));
        const int p = atomicAdd(&cnt[d], 1);
        if (p < BUCKET) gdata[(size_t)d * gstride + p] = rec;
        return;
    }

    if (bid == EDGE_BLOCKS) {  // weight-pack block
        const int t = threadIdx.x;
        const float2* Wn2 = (const float2*)W_neigh;
        const float2* Ws2 = (const float2*)W_self;
        for (int i = t; i < 64 * 128; i += 256) {
            float2 v = Wn2[i];
            wnp[i] = pack_bf16(v.x, v.y);
        }
        for (int i = t; i < 64 * 32; i += 256) {
            float2 v = Ws2[i];
            wsp[i] = pack_bf16(v.x, v.y);
        }
        if (t < 64) bb[t] = b_neigh[t] + bias[t];
        return;
    }

    // feat -> bf16 pack: 4 floats per thread, 3125 blocks exactly
    const int idx = (bid - EDGE_BLOCKS - 1) * 256 + threadIdx.x;  // 0 .. 799999
    float4 v = reinterpret_cast<const float4*>(feat)[idx];
    featb2[idx] = make_uint2(pack_bf16(v.x, v.y), pack_bf16(v.z, v.w));
}

// ---------------- pass 2: fused aggregation + MFMA projection ----------------
// Block = 4 waves = 16 nodes. Wave w aggregates nodes nb+4w..nb+4w+3 (streaming,
// no barriers inside), packs bf16 rows to LDS, then computes its 16-col MFMA tile.

#define ACC_STRIDE 264  // bf16 elements per LDS row (256 + 8 pad; keeps 16B align)

__device__ __forceinline__ float featload(const unsigned short* featb, unsigned rec_y, int lane) {
    return __uint_as_float((unsigned)featb[(size_t)(rec_y >> 16) * 64 + lane] << 16);
}

__global__ __launch_bounds__(256) void aggregate_project_kernel(
    const unsigned short* __restrict__ featb, const float* __restrict__ W_sp,
    const float* __restrict__ b_sp, const int* __restrict__ cnt,
    const uint2* __restrict__ gdata, int gstride, const short* __restrict__ wnb,
    const short* __restrict__ wsb, const float* __restrict__ bb,
    float* __restrict__ out)
{
    __shared__ unsigned short accS[16 * ACC_STRIDE];  // 8448 B

    const int lane = threadIdx.x & 63;
    const int w = threadIdx.x >> 6;
    const int nb = blockIdx.x << 4;  // 3125*16 == 50000 exact

    // per-lane spatial-MLP rows: lane = feature i, handles j = lane*4+h
    float wsp0[4], wsp1[4], wsp2[4], bsp[4];
#pragma unroll
    for (int h = 0; h < 4; ++h) {
        int j = lane * 4 + h;
        wsp0[h] = W_sp[j * 3 + 0];
        wsp1[h] = W_sp[j * 3 + 1];
        wsp2[h] = W_sp[j * 3 + 2];
        bsp[h]  = b_sp[j];
    }

    // ---- aggregation: wave w handles rows 4w..4w+3, one node at a time ----
    for (int q = 0; q < 4; ++q) {
        const int r = (w << 2) + q;
        const int n = nb + r;
        const int degt = __builtin_amdgcn_readfirstlane(cnt[n]);
        const int deg = min(degt, BUCKET);
        const uint2* gp = gdata + (size_t)n * gstride;

        float a0 = 0.f, a1 = 0.f, a2 = 0.f, a3 = 0.f;

        if (deg > 0) {
            const int dm = deg - 1;
            // records 4 ahead, feats 2 ahead: 2 VMEM in flight, full-iter cover
            uint2 u0 = gp[0];
            uint2 u1 = gp[min(1, dm)];
            uint2 u2 = gp[min(2, dm)];
            uint2 u3 = gp[min(3, dm)];
            float f0 = featload(featb, u0.y, lane);
            float f1 = featload(featb, u1.y, lane);

            for (int e = 0; e < deg; e += 2) {
                uint2 u4 = gp[min(e + 4, dm)];
                uint2 u5 = gp[min(e + 5, dm)];
                float f2 = featload(featb, u2.y, lane);
                float f3 = featload(featb, u3.y, lane);

                {
                    const float wx = __uint_as_float(u0.x << 16);
                    const float wy = __uint_as_float(u0.x & 0xffff0000u);
                    const float wz = __uint_as_float(u0.y << 16);
                    float t0 = fmaf(wx, wsp0[0], fmaf(wy, wsp1[0], fmaf(wz, wsp2[0], bsp[0])));
                    float t1 = fmaf(wx, wsp0[1], fmaf(wy, wsp1[1], fmaf(wz, wsp2[1], bsp[1])));
                    float t2 = fmaf(wx, wsp0[2], fmaf(wy, wsp1[2], fmaf(wz, wsp2[2], bsp[2])));
                    float t3 = fmaf(wx, wsp0[3], fmaf(wy, wsp1[3], fmaf(wz, wsp2[3], bsp[3])));
                    a0 = fmaf(fmaxf(t0, t0 * NEG_SLOPE), f0, a0);
                    a1 = fmaf(fmaxf(t1, t1 * NEG_SLOPE), f0, a1);
                    a2 = fmaf(fmaxf(t2, t2 * NEG_SLOPE), f0, a2);
                    a3 = fmaf(fmaxf(t3, t3 * NEG_SLOPE), f0, a3);
                }
                {
                    const float m1 = (e + 1 <= dm) ? 1.f : 0.f;
                    const float fm = f1 * m1;
                    const float wx = __uint_as_float(u1.x << 16);
                    const float wy = __uint_as_float(u1.x & 0xffff0000u);
                    const float wz = __uint_as_float(u1.y << 16);
                    float t0 = fmaf(wx, wsp0[0], fmaf(wy, wsp1[0], fmaf(wz, wsp2[0], bsp[0])));
                    float t1 = fmaf(wx, wsp0[1], fmaf(wy, wsp1[1], fmaf(wz, wsp2[1], bsp[1])));
                    float t2 = fmaf(wx, wsp0[2], fmaf(wy, wsp1[2], fmaf(wz, wsp2[2], bsp[2])));
                    float t3 = fmaf(wx, wsp0[3], fmaf(wy, wsp1[3], fmaf(wz, wsp2[3], bsp[3])));
                    a0 = fmaf(fmaxf(t0, t0 * NEG_SLOPE), fm, a0);
                    a1 = fmaf(fmaxf(t1, t1 * NEG_SLOPE), fm, a1);
                    a2 = fmaf(fmaxf(t2, t2 * NEG_SLOPE), fm, a2);
                    a3 = fmaf(fmaxf(t3, t3 * NEG_SLOPE), fm, a3);
                }

                u0 = u2; u1 = u3; u2 = u4; u3 = u5;
                f0 = f2; f1 = f3;
            }
        }

        const float mscale = 1.f / fmaxf((float)degt, 1.f);
        uint2 pv = make_uint2(pack_bf16(a0 * mscale, a1 * mscale),
                              pack_bf16(a2 * mscale, a3 * mscale));
        *reinterpret_cast<uint2*>(&accS[r * ACC_STRIDE + lane * 4]) = pv;
    }
    __syncthreads();

    // ---- projection: wave w -> output col-tile w (cols w*16..w*16+15) ----
    const int mrow = lane & 15;
    const int quad = lane >> 4;
    const int o = (w << 4) + mrow;

    f32x4 acc = {0.f, 0.f, 0.f, 0.f};

    const unsigned short* Ar = &accS[mrow * ACC_STRIDE + quad * 8];
    const short* Br = wnb + o * 256 + quad * 8;
#pragma unroll
    for (int ks = 0; ks < 8; ++ks) {
        short8 a = *reinterpret_cast<const short8*>(Ar + ks * 32);
        short8 b = *reinterpret_cast<const short8*>(Br + ks * 32);
        acc = __builtin_amdgcn_mfma_f32_16x16x32_bf16(a, b, acc, 0, 0, 0);
    }

    const short* Fr = (const short*)featb + (size_t)(nb + mrow) * 64 + quad * 8;
    const short* Sr = wsb + o * 64 + quad * 8;
#pragma unroll
    for (int ks = 0; ks < 2; ++ks) {
        short8 a = *reinterpret_cast<const short8*>(Fr + ks * 32);
        short8 b = *reinterpret_cast<const short8*>(Sr + ks * 32);
        acc = __builtin_amdgcn_mfma_f32_16x16x32_bf16(a, b, acc, 0, 0, 0);
    }

    const float badd = bb[o];
#pragma unroll
    for (int r = 0; r < 4; ++r) {
        out[(size_t)(nb + quad * 4 + r) * 64 + o] = acc[r] + badd;
    }
}

// ---------------- launch ----------------

extern "C" void kernel_launch(void* const* d_in, const int* in_sizes, int n_in,
                              void* d_out, int out_size, void* d_ws, size_t ws_size,
                              hipStream_t stream) {
    (void)in_sizes; (void)n_in; (void)out_size;
    const float* feat    = (const float*)d_in[0];
    const float* pos     = (const float*)d_in[1];
    const int*   src     = (const int*)d_in[2];
    const int*   dst     = (const int*)d_in[3];
    const float* W_self  = (const float*)d_in[4];
    const float* W_sp    = (const float*)d_in[5];
    const float* b_sp    = (const float*)d_in[6];
    const float* W_neigh = (const float*)d_in[7];
    const float* b_neigh = (const float*)d_in[8];
    const float* bias    = (const float*)d_in[9];
    float* out = (float*)d_out;

    // gstride 72 (de-aliased, 28.8 MB) if scratch allows; else 64 (25.6 MB)
    const size_t tail = (size_t)800000 * 8 + (8192 + 2048 + 64 + N_NODES) * 4 + 256;
    const int gstride = (ws_size >= (size_t)N_NODES * 72 * 8 + tail) ? 72 : BUCKET;

    // ws layout: gdata[N*gstride] uint2 | featb2[800000] uint2 (6.4 MB) |
    //            wnp[8192] | wsp[2048] | bb[64]f | cnt[N]
    uint2*        gdata  = (uint2*)d_ws;
    uint2*        featb2 = gdata + (size_t)N_NODES * gstride;
    unsigned int* wnp    = (unsigned int*)(featb2 + 800000);
    unsigned int* wsp    = wnp + 8192;
    float*        bb     = (float*)(wsp + 2048);
    int*          cnt    = (int*)(bb + 64);

    hipMemsetAsync(cnt, 0, (size_t)N_NODES * sizeof(int), stream);
    prep_kernel<<<EDGE_BLOCKS + 1 + FEAT_BLOCKS, 256, 0, stream>>>(
        src, dst, pos, feat, cnt, gdata, gstride, featb2,
        W_neigh, W_self, b_neigh, bias, wnp, wsp, bb);
    aggregate_project_kernel<<<N_NODES / 16, 256, 0, stream>>>(
        (const unsigned short*)featb2, W_sp, b_sp, cnt, gdata, gstride,
        (const short*)wnp, (const short*)wsp, bb, out);
}